// Round 8
// baseline (561.816 us; speedup 1.0000x reference)
//
#include <hip/hip_runtime.h>
#include <cstdint>

// ---------------------------------------------------------------------------
// GatedMLP: out = relu(relu(x@W1^T+b1) gated-blocksum @ W2^T + b2) @ W3^T
// N=4096, IN=1024, D=2048, G=8, 2D=4096, OUT=1024
// Round 8: resubmission of round-7 kernel (round-7 bench = GPU acquisition
// timeout, kernel never ran).  Change vs round-6 measured baseline:
//   + double-buffered LDS prefetch (issue next-tile global_load_lds BEFORE
//     current tile's ds_read+MFMA; single vmcnt(0)+barrier per K-step).
// Keeps: bf16 pre-cast, gload_lds(16B), 2-way slot swizzle (conflicts=0),
// launch_bounds(256,2).
// ---------------------------------------------------------------------------

#define NP 5120       // padded row space: 4096 + 8*128 slack
#define NROWT 40      // NP / 128
#define NROWS 4096
#define GATES 8

typedef short short8 __attribute__((ext_vector_type(8)));
typedef unsigned short ushort8v __attribute__((ext_vector_type(8)));
typedef float f32x4 __attribute__((ext_vector_type(4)));

constexpr int BM = 128, BN = 128, BK = 32;
constexpr int LDSW_FB = 40;           // fallback: 32 + 8 bf16 pad

__device__ __forceinline__ unsigned short f2b(float f) {
    __bf16 h = (__bf16)f;
    return __builtin_bit_cast(unsigned short, h);
}

// async global->LDS, 16 bytes per lane. LDS dest is wave-uniform base;
// HW writes lane i at base + i*16 (linear).
__device__ __forceinline__ void gload_lds16(const void* g, void* l) {
    __builtin_amdgcn_global_load_lds(
        (const __attribute__((address_space(1))) void*)g,
        (__attribute__((address_space(3))) void*)l, 16, 0, 0);
}

// Swizzle (verified r6: SQ_LDS_BANK_CONFLICT 7.86M -> 0): tile row r
// (64B = four 16B slots), logical slot q stored at q ^ ((r>>1)&3).
// Staging thread t covers (row = t>>2 [+64], slot = t&3):
//   swizzled source slot = (t&3) ^ ((t>>3)&3)
// Read lane: logical q = lane>>4, row = ...+lr (lr=lane&15):
//   slot = (lane>>4) ^ ((lr>>1)&3)

// ---------------------------------------------------------------------------
// Kernel 0: bucket rows by gate id into padded segments (+ zero-row init)
// ---------------------------------------------------------------------------
__global__ void bucket_kernel(const int* __restrict__ gid,
                              int* __restrict__ perm,
                              int* __restrict__ tile_gate,
                              unsigned short* __restrict__ zrow)  // 1024 bf16 or null
{
    __shared__ int cnt[GATES], pstart[GATES], cur[GATES];
    const int t = threadIdx.x;
    if (zrow) {
        ushort4 z; z.x = 0; z.y = 0; z.z = 0; z.w = 0;
        ((ushort4*)zrow)[t] = z;              // 256 threads x 4 = 1024 elems
    }
    if (t < GATES) cnt[t] = 0;
    __syncthreads();
    for (int i = t; i < NROWS; i += 256) atomicAdd(&cnt[gid[i]], 1);
    __syncthreads();
    if (t == 0) {
        int off = 0;
        for (int g = 0; g < GATES; g++) {
            pstart[g] = off;
            cur[g] = 0;
            off += (cnt[g] + 127) & ~127;
        }
    }
    __syncthreads();
    for (int i = t; i < NP; i += 256) perm[i] = -1;
    if (t < NROWT) {
        int r0 = t * 128;
        int tg = 0;
        for (int g = 0; g < GATES; g++) {
            int pc = (cnt[g] + 127) & ~127;
            if (r0 >= pstart[g] && r0 < pstart[g] + pc) tg = g;
        }
        tile_gate[t] = tg;
    }
    __syncthreads();
    for (int i = t; i < NROWS; i += 256) {
        int g = gid[i];
        int p = atomicAdd(&cur[g], 1);
        perm[pstart[g] + p] = i;
    }
}

// ---------------------------------------------------------------------------
// fp32 -> bf16 cast pass (memory-bound, 8 floats/thread/iter)
// ---------------------------------------------------------------------------
__global__ __launch_bounds__(256)
void cast_kernel(const float* __restrict__ src, unsigned short* __restrict__ dst,
                 int n8)
{
    int i = blockIdx.x * 256 + threadIdx.x;
    const int stride = gridDim.x * 256;
    for (; i < n8; i += stride) {
        const float4* s4 = (const float4*)(src + (size_t)i * 8);
        float4 a = s4[0], b = s4[1];
        ushort8v v;
        v[0] = f2b(a.x); v[1] = f2b(a.y); v[2] = f2b(a.z); v[3] = f2b(a.w);
        v[4] = f2b(b.x); v[5] = f2b(b.y); v[6] = f2b(b.z); v[7] = f2b(b.w);
        *(ushort8v*)(dst + (size_t)i * 8) = v;
    }
}

// ---------------------------------------------------------------------------
// FAST PATH GEMMs (double-buffered prefetch)
// ---------------------------------------------------------------------------
__global__ __launch_bounds__(256, 2)
void l1_fast(const unsigned short* __restrict__ xbf,   // [4097][1024], row 4096 = zeros
             const unsigned short* __restrict__ W1bf,  // [36864][1024]
             const float* __restrict__ b1,
             const int* __restrict__ perm,
             const int* __restrict__ tile_gate,
             unsigned short* __restrict__ s_out)       // [NP][4096]
{
    __shared__ __align__(16) unsigned short As[2][BM][BK];
    __shared__ __align__(16) unsigned short Bg[2][BM][BK];
    __shared__ __align__(16) unsigned short Bs[2][BM][BK];

    const int t = threadIdx.x;
    const int rbase = blockIdx.y * BM;
    const int cbase = blockIdx.x * BN;
    const int gate = tile_gate[blockIdx.y];

    const int srow  = t >> 2;                          // 0..63
    const int skcol = ((t & 3) ^ ((t >> 3) & 3)) * 8;  // swizzled source slot

    int g0 = perm[rbase + srow];      if (g0 < 0) g0 = NROWS;
    int g1 = perm[rbase + srow + 64]; if (g1 < 0) g1 = NROWS;

    const unsigned short* a0 = xbf + (size_t)g0 * 1024 + skcol;
    const unsigned short* a1 = xbf + (size_t)g1 * 1024 + skcol;
    const unsigned short* bg0 = W1bf + ((size_t)(gate * 4096 + cbase + srow)) * 1024 + skcol;
    const unsigned short* bg1 = bg0 + (size_t)64 * 1024;
    const unsigned short* bs0 = W1bf + ((size_t)(GATES * 4096 + cbase + srow)) * 1024 + skcol;
    const unsigned short* bs1 = bs0 + (size_t)64 * 1024;

    const int wchunk = (t >> 6) * 1024;   // byte offset of this wave's LDS chunk

    f32x4 accg[4][4], accs[4][4];
#pragma unroll
    for (int m = 0; m < 4; m++)
#pragma unroll
        for (int n = 0; n < 4; n++) {
            accg[m][n] = (f32x4){0.f, 0.f, 0.f, 0.f};
            accs[m][n] = (f32x4){0.f, 0.f, 0.f, 0.f};
        }

    const int lane = t & 63;
    const int wid  = t >> 6;
    const int wr = wid >> 1, wc = wid & 1;
    const int lr = lane & 15;
    const int kb = (((lane >> 4) ^ ((lr >> 1) & 3))) * 8;  // swizzled read slot

    // prologue: stage tile 0 into buffer 0
    gload_lds16(a0,  (char*)As[0] + wchunk);
    gload_lds16(a1,  (char*)As[0] + wchunk + 4096);
    gload_lds16(bg0, (char*)Bg[0] + wchunk);
    gload_lds16(bg1, (char*)Bg[0] + wchunk + 4096);
    gload_lds16(bs0, (char*)Bs[0] + wchunk);
    gload_lds16(bs1, (char*)Bs[0] + wchunk + 4096);
    __syncthreads();

    int cur = 0;
    for (int k0 = 0; k0 < 1024; k0 += BK) {
        // prefetch next tile into the other buffer (before compute)
        const int kn = k0 + BK;
        if (kn < 1024) {
            const int nxt = cur ^ 1;
            gload_lds16(a0 + kn,  (char*)As[nxt] + wchunk);
            gload_lds16(a1 + kn,  (char*)As[nxt] + wchunk + 4096);
            gload_lds16(bg0 + kn, (char*)Bg[nxt] + wchunk);
            gload_lds16(bg1 + kn, (char*)Bg[nxt] + wchunk + 4096);
            gload_lds16(bs0 + kn, (char*)Bs[nxt] + wchunk);
            gload_lds16(bs1 + kn, (char*)Bs[nxt] + wchunk + 4096);
        }

        short8 af[4];
#pragma unroll
        for (int m = 0; m < 4; m++)
            af[m] = *(const short8*)&As[cur][wr * 64 + m * 16 + lr][kb];
        {
            short8 bf[4];
#pragma unroll
            for (int n = 0; n < 4; n++)
                bf[n] = *(const short8*)&Bg[cur][wc * 64 + n * 16 + lr][kb];
#pragma unroll
            for (int m = 0; m < 4; m++)
#pragma unroll
                for (int n = 0; n < 4; n++)
                    accg[m][n] = __builtin_amdgcn_mfma_f32_16x16x32_bf16(
                        af[m], bf[n], accg[m][n], 0, 0, 0);
        }
        {
            short8 bf[4];
#pragma unroll
            for (int n = 0; n < 4; n++)
                bf[n] = *(const short8*)&Bs[cur][wc * 64 + n * 16 + lr][kb];
#pragma unroll
            for (int m = 0; m < 4; m++)
#pragma unroll
                for (int n = 0; n < 4; n++)
                    accs[m][n] = __builtin_amdgcn_mfma_f32_16x16x32_bf16(
                        af[m], bf[n], accs[m][n], 0, 0, 0);
        }
        // drain prefetch (vmcnt) + all ds_reads done (lgkm) before buffer swap
        __syncthreads();
        cur ^= 1;
    }

    const int rowoff = (lane >> 4) * 4;
#pragma unroll
    for (int m = 0; m < 4; m++) {
        const int prow = rbase + wr * 64 + m * 16 + rowoff;
#pragma unroll
        for (int n = 0; n < 4; n++) {
            const int col = cbase + wc * 64 + n * 16 + lr;
            const float b1g = b1[(size_t)gate * 4096 + col];
            const float b1s = b1[(size_t)GATES * 4096 + col];
#pragma unroll
            for (int j = 0; j < 4; j++) {
                float vg = accg[m][n][j] + b1g;
                float vs = accs[m][n][j] + b1s;
                float sv = 0.9f * fmaxf(vg, 0.f) + fmaxf(vs, 0.f);
                s_out[(size_t)(prow + j) * 4096 + col] = f2b(sv);
            }
        }
    }
}

__global__ __launch_bounds__(256, 2)
void l2_fast(const unsigned short* __restrict__ s_in,   // [NP][4096]
             const unsigned short* __restrict__ W2bf,   // [2048][4096]
             const float* __restrict__ b2,
             unsigned short* __restrict__ h2)           // [NP][2048]
{
    __shared__ __align__(16) unsigned short As[2][BM][BK];
    __shared__ __align__(16) unsigned short Bt[2][BM][BK];

    const int t = threadIdx.x;
    const int rbase = blockIdx.y * BM;
    const int cbase = blockIdx.x * BN;
    const int srow  = t >> 2;
    const int skcol = ((t & 3) ^ ((t >> 3) & 3)) * 8;

    const unsigned short* a0 = s_in + (size_t)(rbase + srow) * 4096 + skcol;
    const unsigned short* a1 = a0 + (size_t)64 * 4096;
    const unsigned short* b0 = W2bf + (size_t)(cbase + srow) * 4096 + skcol;
    const unsigned short* b1p = b0 + (size_t)64 * 4096;

    const int wchunk = (t >> 6) * 1024;

    f32x4 acc[4][4];
#pragma unroll
    for (int m = 0; m < 4; m++)
#pragma unroll
        for (int n = 0; n < 4; n++) acc[m][n] = (f32x4){0.f, 0.f, 0.f, 0.f};

    const int lane = t & 63;
    const int wid  = t >> 6;
    const int wr = wid >> 1, wc = wid & 1;
    const int lr = lane & 15;
    const int kb = (((lane >> 4) ^ ((lr >> 1) & 3))) * 8;

    gload_lds16(a0,  (char*)As[0] + wchunk);
    gload_lds16(a1,  (char*)As[0] + wchunk + 4096);
    gload_lds16(b0,  (char*)Bt[0] + wchunk);
    gload_lds16(b1p, (char*)Bt[0] + wchunk + 4096);
    __syncthreads();

    int cur = 0;
    for (int k0 = 0; k0 < 4096; k0 += BK) {
        const int kn = k0 + BK;
        if (kn < 4096) {
            const int nxt = cur ^ 1;
            gload_lds16(a0 + kn,  (char*)As[nxt] + wchunk);
            gload_lds16(a1 + kn,  (char*)As[nxt] + wchunk + 4096);
            gload_lds16(b0 + kn,  (char*)Bt[nxt] + wchunk);
            gload_lds16(b1p + kn, (char*)Bt[nxt] + wchunk + 4096);
        }

        short8 af[4], bf[4];
#pragma unroll
        for (int m = 0; m < 4; m++)
            af[m] = *(const short8*)&As[cur][wr * 64 + m * 16 + lr][kb];
#pragma unroll
        for (int n = 0; n < 4; n++)
            bf[n] = *(const short8*)&Bt[cur][wc * 64 + n * 16 + lr][kb];
#pragma unroll
        for (int m = 0; m < 4; m++)
#pragma unroll
            for (int n = 0; n < 4; n++)
                acc[m][n] = __builtin_amdgcn_mfma_f32_16x16x32_bf16(
                    af[m], bf[n], acc[m][n], 0, 0, 0);
        __syncthreads();
        cur ^= 1;
    }

    const int rowoff = (lane >> 4) * 4;
#pragma unroll
    for (int m = 0; m < 4; m++) {
        const int prow = rbase + wr * 64 + m * 16 + rowoff;
#pragma unroll
        for (int n = 0; n < 4; n++) {
            const int col = cbase + wc * 64 + n * 16 + lr;
            const float bb = b2[col];
#pragma unroll
            for (int j = 0; j < 4; j++) {
                float v = fmaxf(acc[m][n][j] + bb, 0.f);
                h2[(size_t)(prow + j) * 2048 + col] = f2b(v);
            }
        }
    }
}

__global__ __launch_bounds__(256, 2)
void l3_fast(const unsigned short* __restrict__ h2,     // [NP][2048]
             const unsigned short* __restrict__ W3bf,   // [1024][2048]
             const int* __restrict__ perm,
             float* __restrict__ out)                   // [4096][1024]
{
    __shared__ __align__(16) unsigned short As[2][BM][BK];
    __shared__ __align__(16) unsigned short Bt[2][BM][BK];

    const int t = threadIdx.x;
    const int rbase = blockIdx.y * BM;
    const int cbase = blockIdx.x * BN;
    const int srow  = t >> 2;
    const int skcol = ((t & 3) ^ ((t >> 3) & 3)) * 8;

    const unsigned short* a0 = h2 + (size_t)(rbase + srow) * 2048 + skcol;
    const unsigned short* a1 = a0 + (size_t)64 * 2048;
    const unsigned short* b0 = W3bf + (size_t)(cbase + srow) * 2048 + skcol;
    const unsigned short* b1p = b0 + (size_t)64 * 2048;

    const int wchunk = (t >> 6) * 1024;

    f32x4 acc[4][4];
#pragma unroll
    for (int m = 0; m < 4; m++)
#pragma unroll
        for (int n = 0; n < 4; n++) acc[m][n] = (f32x4){0.f, 0.f, 0.f, 0.f};

    const int lane = t & 63;
    const int wid  = t >> 6;
    const int wr = wid >> 1, wc = wid & 1;
    const int lr = lane & 15;
    const int kb = (((lane >> 4) ^ ((lr >> 1) & 3))) * 8;

    gload_lds16(a0,  (char*)As[0] + wchunk);
    gload_lds16(a1,  (char*)As[0] + wchunk + 4096);
    gload_lds16(b0,  (char*)Bt[0] + wchunk);
    gload_lds16(b1p, (char*)Bt[0] + wchunk + 4096);
    __syncthreads();

    int cur = 0;
    for (int k0 = 0; k0 < 2048; k0 += BK) {
        const int kn = k0 + BK;
        if (kn < 2048) {
            const int nxt = cur ^ 1;
            gload_lds16(a0 + kn,  (char*)As[nxt] + wchunk);
            gload_lds16(a1 + kn,  (char*)As[nxt] + wchunk + 4096);
            gload_lds16(b0 + kn,  (char*)Bt[nxt] + wchunk);
            gload_lds16(b1p + kn, (char*)Bt[nxt] + wchunk + 4096);
        }

        short8 af[4], bf[4];
#pragma unroll
        for (int m = 0; m < 4; m++)
            af[m] = *(const short8*)&As[cur][wr * 64 + m * 16 + lr][kb];
#pragma unroll
        for (int n = 0; n < 4; n++)
            bf[n] = *(const short8*)&Bt[cur][wc * 64 + n * 16 + lr][kb];
#pragma unroll
        for (int m = 0; m < 4; m++)
#pragma unroll
            for (int n = 0; n < 4; n++)
                acc[m][n] = __builtin_amdgcn_mfma_f32_16x16x32_bf16(
                    af[m], bf[n], acc[m][n], 0, 0, 0);
        __syncthreads();
        cur ^= 1;
    }

    const int rowoff = (lane >> 4) * 4;
#pragma unroll
    for (int m = 0; m < 4; m++) {
        const int prow = rbase + wr * 64 + m * 16 + rowoff;
#pragma unroll
        for (int n = 0; n < 4; n++) {
            const int col = cbase + wc * 64 + n * 16 + lr;
#pragma unroll
            for (int j = 0; j < 4; j++) {
                int orow = perm[prow + j];
                if (orow >= 0)
                    out[(size_t)orow * 1024 + col] = acc[m][n][j];
            }
        }
    }
}

// ---------------------------------------------------------------------------
// FALLBACK PATH (round-2 verified kernels, fp32 reg-staged)
// ---------------------------------------------------------------------------
__global__ __launch_bounds__(256, 2)
void l1_fb(const float* __restrict__ x, const float* __restrict__ W1,
           const float* __restrict__ b1, const int* __restrict__ perm,
           const int* __restrict__ tile_gate, unsigned short* __restrict__ s_out)
{
    __shared__ __align__(16) unsigned short As[BM][LDSW_FB];
    __shared__ __align__(16) unsigned short Bg[BN][LDSW_FB];
    __shared__ __align__(16) unsigned short Bs[BN][LDSW_FB];

    const int t = threadIdx.x;
    const int rbase = blockIdx.y * BM;
    const int cbase = blockIdx.x * BN;
    const int gate = tile_gate[blockIdx.y];
    const int srow_t = t >> 3;
    const int scol   = (t & 7) * 4;

    int grow[4];
#pragma unroll
    for (int rr = 0; rr < 4; rr++) grow[rr] = perm[rbase + rr * 32 + srow_t];

    const float* Bgp = W1 + ((size_t)gate * 4096 + cbase) * 1024;
    const float* Bsp = W1 + ((size_t)GATES * 4096 + cbase) * 1024;

    f32x4 accg[4][4], accs[4][4];
#pragma unroll
    for (int m = 0; m < 4; m++)
#pragma unroll
        for (int n = 0; n < 4; n++) {
            accg[m][n] = (f32x4){0.f, 0.f, 0.f, 0.f};
            accs[m][n] = (f32x4){0.f, 0.f, 0.f, 0.f};
        }

    const int lane = t & 63;
    const int wid  = t >> 6;
    const int wr = wid >> 1, wc = wid & 1;
    const int lr = lane & 15;
    const int kb = (lane >> 4) * 8;

    for (int k0 = 0; k0 < 1024; k0 += BK) {
        __syncthreads();
#pragma unroll
        for (int rr = 0; rr < 4; rr++) {
            const int row = rr * 32 + srow_t;
            float4 av = make_float4(0.f, 0.f, 0.f, 0.f);
            if (grow[rr] >= 0)
                av = *(const float4*)(x + (size_t)grow[rr] * 1024 + k0 + scol);
            ushort4 pa;
            pa.x = f2b(av.x); pa.y = f2b(av.y); pa.z = f2b(av.z); pa.w = f2b(av.w);
            *(ushort4*)&As[row][scol] = pa;

            float4 gv = *(const float4*)(Bgp + (size_t)row * 1024 + k0 + scol);
            ushort4 pg;
            pg.x = f2b(gv.x); pg.y = f2b(gv.y); pg.z = f2b(gv.z); pg.w = f2b(gv.w);
            *(ushort4*)&Bg[row][scol] = pg;

            float4 sv = *(const float4*)(Bsp + (size_t)row * 1024 + k0 + scol);
            ushort4 ps;
            ps.x = f2b(sv.x); ps.y = f2b(sv.y); ps.z = f2b(sv.z); ps.w = f2b(sv.w);
            *(ushort4*)&Bs[row][scol] = ps;
        }
        __syncthreads();

        short8 af[4], bgf[4], bsf[4];
#pragma unroll
        for (int m = 0; m < 4; m++)
            af[m] = *(const short8*)&As[wr * 64 + m * 16 + lr][kb];
#pragma unroll
        for (int n = 0; n < 4; n++) {
            bgf[n] = *(const short8*)&Bg[wc * 64 + n * 16 + lr][kb];
            bsf[n] = *(const short8*)&Bs[wc * 64 + n * 16 + lr][kb];
        }
#pragma unroll
        for (int m = 0; m < 4; m++)
#pragma unroll
            for (int n = 0; n < 4; n++) {
                accg[m][n] = __builtin_amdgcn_mfma_f32_16x16x32_bf16(
                    af[m], bgf[n], accg[m][n], 0, 0, 0);
                accs[m][n] = __builtin_amdgcn_mfma_f32_16x16x32_bf16(
                    af[m], bsf[n], accs[m][n], 0, 0, 0);
            }
    }

    const int rowoff = (lane >> 4) * 4;
#pragma unroll
    for (int m = 0; m < 4; m++) {
        const int prow = rbase + wr * 64 + m * 16 + rowoff;
#pragma unroll
        for (int n = 0; n < 4; n++) {
            const int col = cbase + wc * 64 + n * 16 + lr;
            const float b1g = b1[(size_t)gate * 4096 + col];
            const float b1s = b1[(size_t)GATES * 4096 + col];
#pragma unroll
            for (int j = 0; j < 4; j++) {
                float vg = accg[m][n][j] + b1g;
                float vs = accs[m][n][j] + b1s;
                float sv = 0.9f * fmaxf(vg, 0.f) + fmaxf(vs, 0.f);
                s_out[(size_t)(prow + j) * 4096 + col] = f2b(sv);
            }
        }
    }
}

__global__ __launch_bounds__(256, 2)
void l2_fb(const unsigned short* __restrict__ s_in, const float* __restrict__ W2,
           const float* __restrict__ b2, unsigned short* __restrict__ h2)
{
    __shared__ __align__(16) unsigned short As[BM][LDSW_FB];
    __shared__ __align__(16) unsigned short Bt[BN][LDSW_FB];

    const int t = threadIdx.x;
    const int rbase = blockIdx.y * BM;
    const int cbase = blockIdx.x * BN;
    const int srow_t = t >> 3;
    const int scol   = (t & 7) * 4;

    f32x4 acc[4][4];
#pragma unroll
    for (int m = 0; m < 4; m++)
#pragma unroll
        for (int n = 0; n < 4; n++) acc[m][n] = (f32x4){0.f, 0.f, 0.f, 0.f};

    const int lane = t & 63;
    const int wid  = t >> 6;
    const int wr = wid >> 1, wc = wid & 1;
    const int lr = lane & 15;
    const int kb = (lane >> 4) * 8;

    for (int k0 = 0; k0 < 4096; k0 += BK) {
        __syncthreads();
#pragma unroll
        for (int rr = 0; rr < 4; rr++) {
            const int row = rr * 32 + srow_t;
            ushort4 av = *(const ushort4*)(s_in + (size_t)(rbase + row) * 4096 + k0 + scol);
            *(ushort4*)&As[row][scol] = av;
            float4 bv = *(const float4*)(W2 + (size_t)(cbase + row) * 4096 + k0 + scol);
            ushort4 pb;
            pb.x = f2b(bv.x); pb.y = f2b(bv.y); pb.z = f2b(bv.z); pb.w = f2b(bv.w);
            *(ushort4*)&Bt[row][scol] = pb;
        }
        __syncthreads();

        short8 af[4], bf[4];
#pragma unroll
        for (int m = 0; m < 4; m++)
            af[m] = *(const short8*)&As[wr * 64 + m * 16 + lr][kb];
#pragma unroll
        for (int n = 0; n < 4; n++)
            bf[n] = *(const short8*)&Bt[wc * 64 + n * 16 + lr][kb];
#pragma unroll
        for (int m = 0; m < 4; m++)
#pragma unroll
            for (int n = 0; n < 4; n++)
                acc[m][n] = __builtin_amdgcn_mfma_f32_16x16x32_bf16(
                    af[m], bf[n], acc[m][n], 0, 0, 0);
    }

    const int rowoff = (lane >> 4) * 4;
#pragma unroll
    for (int m = 0; m < 4; m++) {
        const int prow = rbase + wr * 64 + m * 16 + rowoff;
#pragma unroll
        for (int n = 0; n < 4; n++) {
            const int col = cbase + wc * 64 + n * 16 + lr;
            const float bb = b2[col];
#pragma unroll
            for (int j = 0; j < 4; j++) {
                float v = fmaxf(acc[m][n][j] + bb, 0.f);
                h2[(size_t)(prow + j) * 2048 + col] = f2b(v);
            }
        }
    }
}

__global__ __launch_bounds__(256, 2)
void l3_fb(const unsigned short* __restrict__ h2, const float* __restrict__ W3,
           const int* __restrict__ perm, float* __restrict__ out)
{
    __shared__ __align__(16) unsigned short As[BM][LDSW_FB];
    __shared__ __align__(16) unsigned short Bt[BN][LDSW_FB];

    const int t = threadIdx.x;
    const int rbase = blockIdx.y * BM;
    const int cbase = blockIdx.x * BN;
    const int srow_t = t >> 3;
    const int scol   = (t & 7) * 4;

    f32x4 acc[4][4];
#pragma unroll
    for (int m = 0; m < 4; m++)
#pragma unroll
        for (int n = 0; n < 4; n++) acc[m][n] = (f32x4){0.f, 0.f, 0.f, 0.f};

    const int lane = t & 63;
    const int wid  = t >> 6;
    const int wr = wid >> 1, wc = wid & 1;
    const int lr = lane & 15;
    const int kb = (lane >> 4) * 8;

    for (int k0 = 0; k0 < 2048; k0 += BK) {
        __syncthreads();
#pragma unroll
        for (int rr = 0; rr < 4; rr++) {
            const int row = rr * 32 + srow_t;
            ushort4 av = *(const ushort4*)(h2 + (size_t)(rbase + row) * 2048 + k0 + scol);
            *(ushort4*)&As[row][scol] = av;
            float4 bv = *(const float4*)(W3 + (size_t)(cbase + row) * 2048 + k0 + scol);
            ushort4 pb;
            pb.x = f2b(bv.x); pb.y = f2b(bv.y); pb.z = f2b(bv.z); pb.w = f2b(bv.w);
            *(ushort4*)&Bt[row][scol] = pb;
        }
        __syncthreads();

        short8 af[4], bf[4];
#pragma unroll
        for (int m = 0; m < 4; m++)
            af[m] = *(const short8*)&As[wr * 64 + m * 16 + lr][kb];
#pragma unroll
        for (int n = 0; n < 4; n++)
            bf[n] = *(const short8*)&Bt[wc * 64 + n * 16 + lr][kb];
#pragma unroll
        for (int m = 0; m < 4; m++)
#pragma unroll
            for (int n = 0; n < 4; n++)
                acc[m][n] = __builtin_amdgcn_mfma_f32_16x16x32_bf16(
                    af[m], bf[n], acc[m][n], 0, 0, 0);
    }

    const int rowoff = (lane >> 4) * 4;
#pragma unroll
    for (int m = 0; m < 4; m++) {
        const int prow = rbase + wr * 64 + m * 16 + rowoff;
#pragma unroll
        for (int n = 0; n < 4; n++) {
            const int col = cbase + wc * 64 + n * 16 + lr;
#pragma unroll
            for (int j = 0; j < 4; j++) {
                int orow = perm[prow + j];
                if (orow >= 0)
                    out[(size_t)orow * 1024 + col] = acc[m][n][j];
            }
        }
    }
}

// ---------------------------------------------------------------------------
extern "C" void kernel_launch(void* const* d_in, const int* in_sizes, int n_in,
                              void* d_out, int out_size, void* d_ws, size_t ws_size,
                              hipStream_t stream)
{
    const float* x   = (const float*)d_in[0];
    const int*   gid = (const int*)d_in[1];
    const float* W1  = (const float*)d_in[2];
    const float* b1  = (const float*)d_in[3];
    const float* W2  = (const float*)d_in[4];
    const float* b2  = (const float*)d_in[5];
    const float* W3  = (const float*)d_in[6];
    float* out = (float*)d_out;
    char* ws = (char*)d_ws;

    auto alignup = [](size_t v) { return (v + 255) & ~(size_t)255; };

    // ---- big (fast-path) layout ----
    size_t off = 0;
    const size_t perm_off = off; off = alignup(off + (size_t)NP * 4);
    const size_t tg_off   = off; off = alignup(off + (size_t)NROWT * 4);
    const size_t xbf_off  = off; off = alignup(off + (size_t)4097 * 1024 * 2);
    const size_t w1_off   = off; off = alignup(off + (size_t)36864 * 1024 * 2);
    const size_t w2_off   = off; off = alignup(off + (size_t)2048 * 4096 * 2);
    const size_t w3_off   = off; off = alignup(off + (size_t)1024 * 2048 * 2);
    const size_t sB_off   = off; off = alignup(off + (size_t)NP * 4096 * 2);
    const size_t h2B_off  = off; off = alignup(off + (size_t)NP * 2048 * 2);
    const size_t need_big = off;

    // ---- small (fallback) layout (round-2 verified) ----
    const size_t sS_off   = 32768;
    const size_t h2S_off  = sS_off + (size_t)NP * 4096 * 2;
    const size_t need_sm  = h2S_off + (size_t)NP * 2048 * 2;

    int* perm = (int*)(ws + perm_off);
    int* tile_gate = (int*)(ws + tg_off);

    if (ws_size >= need_big) {
        unsigned short* xbf  = (unsigned short*)(ws + xbf_off);
        unsigned short* w1bf = (unsigned short*)(ws + w1_off);
        unsigned short* w2bf = (unsigned short*)(ws + w2_off);
        unsigned short* w3bf = (unsigned short*)(ws + w3_off);
        unsigned short* s_perm = (unsigned short*)(ws + sB_off);
        unsigned short* h2 = (unsigned short*)(ws + h2B_off);
        unsigned short* zrow = xbf + (size_t)NROWS * 1024;   // row 4096

        bucket_kernel<<<1, 256, 0, stream>>>(gid, perm, tile_gate, zrow);
        cast_kernel<<<2048, 256, 0, stream>>>(x,  xbf,  (NROWS * 1024) / 8);
        cast_kernel<<<2048, 256, 0, stream>>>(W1, w1bf, (36864 * 1024) / 8);
        cast_kernel<<<2048, 256, 0, stream>>>(W2, w2bf, (2048 * 4096) / 8);
        cast_kernel<<<1024, 256, 0, stream>>>(W3, w3bf, (1024 * 2048) / 8);
        l1_fast<<<dim3(32, NROWT), 256, 0, stream>>>(xbf, w1bf, b1, perm, tile_gate, s_perm);
        l2_fast<<<dim3(16, NROWT), 256, 0, stream>>>(s_perm, w2bf, b2, h2);
        l3_fast<<<dim3(8, NROWT), 256, 0, stream>>>(h2, w3bf, perm, out);
    } else if (ws_size >= need_sm) {
        // fallback: round-2 path, perm/tg at same offsets (0 / 20480)
        unsigned short* s_perm = (unsigned short*)(ws + sS_off);
        unsigned short* h2 = (unsigned short*)(ws + h2S_off);

        bucket_kernel<<<1, 256, 0, stream>>>(gid, perm, tile_gate, (unsigned short*)nullptr);
        l1_fb<<<dim3(32, NROWT), 256, 0, stream>>>(x, W1, b1, perm, tile_gate, s_perm);
        l2_fb<<<dim3(16, NROWT), 256, 0, stream>>>(s_perm, W2, b2, h2);
        l3_fb<<<dim3(8, NROWT), 256, 0, stream>>>(h2, W3, perm, out);
    }
    // else: ws too small even for fallback -> loud failure
}

// Round 9
// 548.969 us; speedup vs baseline: 1.0234x; 1.0234x over previous
//
#include <hip/hip_runtime.h>
#include <cstdint>

// ---------------------------------------------------------------------------
// GatedMLP: out = relu(relu(x@W1^T+b1) gated-blocksum @ W2^T + b2) @ W3^T
// N=4096, IN=1024, D=2048, G=8, 2D=4096, OUT=1024
// Round 9 (on round-6 measured base; dbuf of r8 reverted as neutral-neg):
//   + fully-pad row-tile early exit (perm[rbase]<0 => whole tile pad)
//   + XCD-aware bijective block swizzle (grids all %8==0)
//   + l3 retiled 128x64 (grid 320->640, fixes 1.25 blocks/CU)
//   + merged cast kernel (one launch for x,W1,W2,W3)
// Keeps: bf16 pre-cast, gload_lds(16B), 2-way slot swizzle (conflicts=0),
// launch_bounds(256,2) on l1/l2.
// ---------------------------------------------------------------------------

#define NP 5120       // padded row space: 4096 + 8*128 slack
#define NROWT 40      // NP / 128
#define NROWS 4096
#define GATES 8

typedef short short8 __attribute__((ext_vector_type(8)));
typedef unsigned short ushort8v __attribute__((ext_vector_type(8)));
typedef float f32x4 __attribute__((ext_vector_type(4)));

constexpr int BM = 128, BN = 128, BK = 32;
constexpr int BN3 = 64;               // l3 column-tile
constexpr int LDSW_FB = 40;           // fallback: 32 + 8 bf16 pad

__device__ __forceinline__ unsigned short f2b(float f) {
    __bf16 h = (__bf16)f;
    return __builtin_bit_cast(unsigned short, h);
}

// async global->LDS, 16 bytes per lane. LDS dest is wave-uniform base;
// HW writes lane i at base + i*16 (linear).
__device__ __forceinline__ void gload_lds16(const void* g, void* l) {
    __builtin_amdgcn_global_load_lds(
        (const __attribute__((address_space(1))) void*)g,
        (__attribute__((address_space(3))) void*)l, 16, 0, 0);
}

// XCD-aware bijective block remap (grid size divisible by 8).
// HW ids {i, i+8, ...} share an XCD; map them to contiguous logical tiles.
__device__ __forceinline__ void xcd_remap(int gx, int& bx, int& by) {
    const int n = gx * gridDim.y;
    const int lin = by * gx + bx;
    const int s = (lin & 7) * (n >> 3) + (lin >> 3);
    bx = s % gx;
    by = s / gx;
}

// LDS slot swizzle (verified r6: SQ_LDS_BANK_CONFLICT 7.86M -> 0): tile row r
// (64B = four 16B slots), logical slot q stored at q ^ ((r>>1)&3).
// Staging thread t (row = t>>2 [+64], slot = t&3):
//   swizzled source slot = (t&3) ^ ((t>>3)&3)
// Read lane (row = 16*q + lr, lr = lane&15):
//   slot = (lane>>4) ^ ((lr>>1)&3)

// ---------------------------------------------------------------------------
// Kernel 0: bucket rows by gate id into padded segments (+ zero-row init)
// ---------------------------------------------------------------------------
__global__ void bucket_kernel(const int* __restrict__ gid,
                              int* __restrict__ perm,
                              int* __restrict__ tile_gate,
                              unsigned short* __restrict__ zrow)  // 1024 bf16 or null
{
    __shared__ int cnt[GATES], pstart[GATES], cur[GATES];
    const int t = threadIdx.x;
    if (zrow) {
        ushort4 z; z.x = 0; z.y = 0; z.z = 0; z.w = 0;
        ((ushort4*)zrow)[t] = z;              // 256 threads x 4 = 1024 elems
    }
    if (t < GATES) cnt[t] = 0;
    __syncthreads();
    for (int i = t; i < NROWS; i += 256) atomicAdd(&cnt[gid[i]], 1);
    __syncthreads();
    if (t == 0) {
        int off = 0;
        for (int g = 0; g < GATES; g++) {
            pstart[g] = off;
            cur[g] = 0;
            off += (cnt[g] + 127) & ~127;
        }
    }
    __syncthreads();
    for (int i = t; i < NP; i += 256) perm[i] = -1;
    if (t < NROWT) {
        int r0 = t * 128;
        int tg = 0;
        for (int g = 0; g < GATES; g++) {
            int pc = (cnt[g] + 127) & ~127;
            if (r0 >= pstart[g] && r0 < pstart[g] + pc) tg = g;
        }
        tile_gate[t] = tg;
    }
    __syncthreads();
    for (int i = t; i < NROWS; i += 256) {
        int g = gid[i];
        int p = atomicAdd(&cur[g], 1);
        perm[pstart[g] + p] = i;
    }
}

// ---------------------------------------------------------------------------
// merged fp32 -> bf16 cast pass over 4 arrays (memory-bound, 8 f32/iter)
// ---------------------------------------------------------------------------
__global__ __launch_bounds__(256)
void cast_all_kernel(const float* __restrict__ s0, unsigned short* __restrict__ d0, int n0,
                     const float* __restrict__ s1, unsigned short* __restrict__ d1, int n1,
                     const float* __restrict__ s2, unsigned short* __restrict__ d2, int n2,
                     const float* __restrict__ s3, unsigned short* __restrict__ d3, int n3)
{
    const int e01 = n0 + n1, e012 = n0 + n1 + n2;
    const int total = e012 + n3;
    int i = blockIdx.x * 256 + threadIdx.x;
    const int stride = gridDim.x * 256;
    for (; i < total; i += stride) {
        const float* s; unsigned short* d; int j;
        if (i < n0)        { s = s0; d = d0; j = i; }
        else if (i < e01)  { s = s1; d = d1; j = i - n0; }
        else if (i < e012) { s = s2; d = d2; j = i - e01; }
        else               { s = s3; d = d3; j = i - e012; }
        const float4* s4 = (const float4*)(s + (size_t)j * 8);
        float4 a = s4[0], b = s4[1];
        ushort8v v;
        v[0] = f2b(a.x); v[1] = f2b(a.y); v[2] = f2b(a.z); v[3] = f2b(a.w);
        v[4] = f2b(b.x); v[5] = f2b(b.y); v[6] = f2b(b.z); v[7] = f2b(b.w);
        *(ushort8v*)(d + (size_t)j * 8) = v;
    }
}

// ---------------------------------------------------------------------------
// FAST PATH GEMMs (single-buffer round-6 loop + early-exit + XCD swizzle)
// ---------------------------------------------------------------------------
__global__ __launch_bounds__(256, 2)
void l1_fast(const unsigned short* __restrict__ xbf,   // [4097][1024], row 4096 = zeros
             const unsigned short* __restrict__ W1bf,  // [36864][1024]
             const float* __restrict__ b1,
             const int* __restrict__ perm,
             const int* __restrict__ tile_gate,
             unsigned short* __restrict__ s_out)       // [NP][4096]
{
    __shared__ __align__(16) unsigned short As[BM][BK];
    __shared__ __align__(16) unsigned short Bg[BN][BK];
    __shared__ __align__(16) unsigned short Bs[BN][BK];

    int bx = blockIdx.x, by = blockIdx.y;
    xcd_remap(32, bx, by);                  // grid (32,40) = 1280, %8==0
    const int rbase = by * BM;
    if (perm[rbase] < 0) return;            // fully-pad row tile
    const int cbase = bx * BN;
    const int gate = tile_gate[by];

    const int t = threadIdx.x;
    const int srow  = t >> 2;                          // 0..63
    const int skcol = ((t & 3) ^ ((t >> 3) & 3)) * 8;  // swizzled source slot

    int g0 = perm[rbase + srow];      if (g0 < 0) g0 = NROWS;
    int g1 = perm[rbase + srow + 64]; if (g1 < 0) g1 = NROWS;

    const unsigned short* a0 = xbf + (size_t)g0 * 1024 + skcol;
    const unsigned short* a1 = xbf + (size_t)g1 * 1024 + skcol;
    const unsigned short* bg0 = W1bf + ((size_t)(gate * 4096 + cbase + srow)) * 1024 + skcol;
    const unsigned short* bg1 = bg0 + (size_t)64 * 1024;
    const unsigned short* bs0 = W1bf + ((size_t)(GATES * 4096 + cbase + srow)) * 1024 + skcol;
    const unsigned short* bs1 = bs0 + (size_t)64 * 1024;

    const int wchunk = (t >> 6) * 1024;   // byte offset of this wave's LDS chunk

    f32x4 accg[4][4], accs[4][4];
#pragma unroll
    for (int m = 0; m < 4; m++)
#pragma unroll
        for (int n = 0; n < 4; n++) {
            accg[m][n] = (f32x4){0.f, 0.f, 0.f, 0.f};
            accs[m][n] = (f32x4){0.f, 0.f, 0.f, 0.f};
        }

    const int lane = t & 63;
    const int wid  = t >> 6;
    const int wr = wid >> 1, wc = wid & 1;
    const int lr = lane & 15;
    const int kb = (((lane >> 4) ^ ((lr >> 1) & 3))) * 8;  // swizzled read slot

    for (int k0 = 0; k0 < 1024; k0 += BK) {
        gload_lds16(a0 + k0,  (char*)As + wchunk);
        gload_lds16(a1 + k0,  (char*)As + wchunk + 4096);
        gload_lds16(bg0 + k0, (char*)Bg + wchunk);
        gload_lds16(bg1 + k0, (char*)Bg + wchunk + 4096);
        gload_lds16(bs0 + k0, (char*)Bs + wchunk);
        gload_lds16(bs1 + k0, (char*)Bs + wchunk + 4096);
        __syncthreads();   // drains vmcnt before barrier

        short8 af[4];
#pragma unroll
        for (int m = 0; m < 4; m++)
            af[m] = *(const short8*)&As[wr * 64 + m * 16 + lr][kb];
        {
            short8 bf[4];
#pragma unroll
            for (int n = 0; n < 4; n++)
                bf[n] = *(const short8*)&Bg[wc * 64 + n * 16 + lr][kb];
#pragma unroll
            for (int m = 0; m < 4; m++)
#pragma unroll
                for (int n = 0; n < 4; n++)
                    accg[m][n] = __builtin_amdgcn_mfma_f32_16x16x32_bf16(
                        af[m], bf[n], accg[m][n], 0, 0, 0);
        }
        {
            short8 bf[4];
#pragma unroll
            for (int n = 0; n < 4; n++)
                bf[n] = *(const short8*)&Bs[wc * 64 + n * 16 + lr][kb];
#pragma unroll
            for (int m = 0; m < 4; m++)
#pragma unroll
                for (int n = 0; n < 4; n++)
                    accs[m][n] = __builtin_amdgcn_mfma_f32_16x16x32_bf16(
                        af[m], bf[n], accs[m][n], 0, 0, 0);
        }
        __syncthreads();
    }

    const int rowoff = (lane >> 4) * 4;
#pragma unroll
    for (int m = 0; m < 4; m++) {
        const int prow = rbase + wr * 64 + m * 16 + rowoff;
#pragma unroll
        for (int n = 0; n < 4; n++) {
            const int col = cbase + wc * 64 + n * 16 + lr;
            const float b1g = b1[(size_t)gate * 4096 + col];
            const float b1s = b1[(size_t)GATES * 4096 + col];
#pragma unroll
            for (int j = 0; j < 4; j++) {
                float vg = accg[m][n][j] + b1g;
                float vs = accs[m][n][j] + b1s;
                float sv = 0.9f * fmaxf(vg, 0.f) + fmaxf(vs, 0.f);
                s_out[(size_t)(prow + j) * 4096 + col] = f2b(sv);
            }
        }
    }
}

__global__ __launch_bounds__(256, 2)
void l2_fast(const unsigned short* __restrict__ s_in,   // [NP][4096]
             const unsigned short* __restrict__ W2bf,   // [2048][4096]
             const float* __restrict__ b2,
             const int* __restrict__ perm,
             unsigned short* __restrict__ h2)           // [NP][2048]
{
    __shared__ __align__(16) unsigned short As[BM][BK];
    __shared__ __align__(16) unsigned short Bt[BN][BK];

    int bx = blockIdx.x, by = blockIdx.y;
    xcd_remap(16, bx, by);                  // grid (16,40) = 640, %8==0
    const int rbase = by * BM;
    if (perm[rbase] < 0) return;            // fully-pad row tile
    const int cbase = bx * BN;

    const int t = threadIdx.x;
    const int srow  = t >> 2;
    const int skcol = ((t & 3) ^ ((t >> 3) & 3)) * 8;

    const unsigned short* a0 = s_in + (size_t)(rbase + srow) * 4096 + skcol;
    const unsigned short* a1 = a0 + (size_t)64 * 4096;
    const unsigned short* b0 = W2bf + (size_t)(cbase + srow) * 4096 + skcol;
    const unsigned short* b1p = b0 + (size_t)64 * 4096;

    const int wchunk = (t >> 6) * 1024;

    f32x4 acc[4][4];
#pragma unroll
    for (int m = 0; m < 4; m++)
#pragma unroll
        for (int n = 0; n < 4; n++) acc[m][n] = (f32x4){0.f, 0.f, 0.f, 0.f};

    const int lane = t & 63;
    const int wid  = t >> 6;
    const int wr = wid >> 1, wc = wid & 1;
    const int lr = lane & 15;
    const int kb = (((lane >> 4) ^ ((lr >> 1) & 3))) * 8;

    for (int k0 = 0; k0 < 4096; k0 += BK) {
        gload_lds16(a0 + k0,  (char*)As + wchunk);
        gload_lds16(a1 + k0,  (char*)As + wchunk + 4096);
        gload_lds16(b0 + k0,  (char*)Bt + wchunk);
        gload_lds16(b1p + k0, (char*)Bt + wchunk + 4096);
        __syncthreads();

        short8 af[4], bf[4];
#pragma unroll
        for (int m = 0; m < 4; m++)
            af[m] = *(const short8*)&As[wr * 64 + m * 16 + lr][kb];
#pragma unroll
        for (int n = 0; n < 4; n++)
            bf[n] = *(const short8*)&Bt[wc * 64 + n * 16 + lr][kb];
#pragma unroll
        for (int m = 0; m < 4; m++)
#pragma unroll
            for (int n = 0; n < 4; n++)
                acc[m][n] = __builtin_amdgcn_mfma_f32_16x16x32_bf16(
                    af[m], bf[n], acc[m][n], 0, 0, 0);
        __syncthreads();
    }

    const int rowoff = (lane >> 4) * 4;
#pragma unroll
    for (int m = 0; m < 4; m++) {
        const int prow = rbase + wr * 64 + m * 16 + rowoff;
#pragma unroll
        for (int n = 0; n < 4; n++) {
            const int col = cbase + wc * 64 + n * 16 + lr;
            const float bb = b2[col];
#pragma unroll
            for (int j = 0; j < 4; j++) {
                float v = fmaxf(acc[m][n][j] + bb, 0.f);
                h2[(size_t)(prow + j) * 2048 + col] = f2b(v);
            }
        }
    }
}

// l3: 128x64 tiles, grid (1024/64=16, 40) = 640 blocks. Per wave (2x2): 64x32,
// acc[4][2] = 32 AGPR; ~<=100 unified regs -> (256,4) safe (no spill).
__global__ __launch_bounds__(256, 4)
void l3_fast(const unsigned short* __restrict__ h2,     // [NP][2048]
             const unsigned short* __restrict__ W3bf,   // [1024][2048]
             const int* __restrict__ perm,
             float* __restrict__ out)                   // [4096][1024]
{
    __shared__ __align__(16) unsigned short As[BM][BK];   // 8 KB
    __shared__ __align__(16) unsigned short Bt[BN3][BK];  // 4 KB

    int bx = blockIdx.x, by = blockIdx.y;
    xcd_remap(16, bx, by);                  // grid (16,40) = 640, %8==0
    const int rbase = by * BM;
    if (perm[rbase] < 0) return;            // fully-pad row tile
    const int cbase = bx * BN3;

    const int t = threadIdx.x;
    const int srow  = t >> 2;
    const int skcol = ((t & 3) ^ ((t >> 3) & 3)) * 8;

    const unsigned short* a0 = h2 + (size_t)(rbase + srow) * 2048 + skcol;
    const unsigned short* a1 = a0 + (size_t)64 * 2048;
    const unsigned short* b0 = W3bf + (size_t)(cbase + srow) * 2048 + skcol; // srow<64 rows

    const int wchunk = (t >> 6) * 1024;

    f32x4 acc[4][2];
#pragma unroll
    for (int m = 0; m < 4; m++)
#pragma unroll
        for (int n = 0; n < 2; n++) acc[m][n] = (f32x4){0.f, 0.f, 0.f, 0.f};

    const int lane = t & 63;
    const int wid  = t >> 6;
    const int wr = wid >> 1, wc = wid & 1;
    const int lr = lane & 15;
    const int kb = (((lane >> 4) ^ ((lr >> 1) & 3))) * 8;

    for (int k0 = 0; k0 < 2048; k0 += BK) {
        gload_lds16(a0 + k0, (char*)As + wchunk);
        gload_lds16(a1 + k0, (char*)As + wchunk + 4096);
        gload_lds16(b0 + k0, (char*)Bt + wchunk);      // 4 waves x 1KB = 4KB tile
        __syncthreads();

        short8 af[4], bf[2];
#pragma unroll
        for (int m = 0; m < 4; m++)
            af[m] = *(const short8*)&As[wr * 64 + m * 16 + lr][kb];
#pragma unroll
        for (int n = 0; n < 2; n++)
            bf[n] = *(const short8*)&Bt[wc * 32 + n * 16 + lr][kb];
#pragma unroll
        for (int m = 0; m < 4; m++)
#pragma unroll
            for (int n = 0; n < 2; n++)
                acc[m][n] = __builtin_amdgcn_mfma_f32_16x16x32_bf16(
                    af[m], bf[n], acc[m][n], 0, 0, 0);
        __syncthreads();
    }

    const int rowoff = (lane >> 4) * 4;
#pragma unroll
    for (int m = 0; m < 4; m++) {
        const int prow = rbase + wr * 64 + m * 16 + rowoff;
#pragma unroll
        for (int n = 0; n < 2; n++) {
            const int col = cbase + wc * 32 + n * 16 + lr;
#pragma unroll
            for (int j = 0; j < 4; j++) {
                int orow = perm[prow + j];
                if (orow >= 0)
                    out[(size_t)orow * 1024 + col] = acc[m][n][j];
            }
        }
    }
}

// ---------------------------------------------------------------------------
// FALLBACK PATH (round-2 verified kernels, fp32 reg-staged)
// ---------------------------------------------------------------------------
__global__ __launch_bounds__(256, 2)
void l1_fb(const float* __restrict__ x, const float* __restrict__ W1,
           const float* __restrict__ b1, const int* __restrict__ perm,
           const int* __restrict__ tile_gate, unsigned short* __restrict__ s_out)
{
    __shared__ __align__(16) unsigned short As[BM][LDSW_FB];
    __shared__ __align__(16) unsigned short Bg[BN][LDSW_FB];
    __shared__ __align__(16) unsigned short Bs[BN][LDSW_FB];

    const int t = threadIdx.x;
    const int rbase = blockIdx.y * BM;
    const int cbase = blockIdx.x * BN;
    const int gate = tile_gate[blockIdx.y];
    const int srow_t = t >> 3;
    const int scol   = (t & 7) * 4;

    int grow[4];
#pragma unroll
    for (int rr = 0; rr < 4; rr++) grow[rr] = perm[rbase + rr * 32 + srow_t];

    const float* Bgp = W1 + ((size_t)gate * 4096 + cbase) * 1024;
    const float* Bsp = W1 + ((size_t)GATES * 4096 + cbase) * 1024;

    f32x4 accg[4][4], accs[4][4];
#pragma unroll
    for (int m = 0; m < 4; m++)
#pragma unroll
        for (int n = 0; n < 4; n++) {
            accg[m][n] = (f32x4){0.f, 0.f, 0.f, 0.f};
            accs[m][n] = (f32x4){0.f, 0.f, 0.f, 0.f};
        }

    const int lane = t & 63;
    const int wid  = t >> 6;
    const int wr = wid >> 1, wc = wid & 1;
    const int lr = lane & 15;
    const int kb = (lane >> 4) * 8;

    for (int k0 = 0; k0 < 1024; k0 += BK) {
        __syncthreads();
#pragma unroll
        for (int rr = 0; rr < 4; rr++) {
            const int row = rr * 32 + srow_t;
            float4 av = make_float4(0.f, 0.f, 0.f, 0.f);
            if (grow[rr] >= 0)
                av = *(const float4*)(x + (size_t)grow[rr] * 1024 + k0 + scol);
            ushort4 pa;
            pa.x = f2b(av.x); pa.y = f2b(av.y); pa.z = f2b(av.z); pa.w = f2b(av.w);
            *(ushort4*)&As[row][scol] = pa;

            float4 gv = *(const float4*)(Bgp + (size_t)row * 1024 + k0 + scol);
            ushort4 pg;
            pg.x = f2b(gv.x); pg.y = f2b(gv.y); pg.z = f2b(gv.z); pg.w = f2b(gv.w);
            *(ushort4*)&Bg[row][scol] = pg;

            float4 sv = *(const float4*)(Bsp + (size_t)row * 1024 + k0 + scol);
            ushort4 ps;
            ps.x = f2b(sv.x); ps.y = f2b(sv.y); ps.z = f2b(sv.z); ps.w = f2b(sv.w);
            *(ushort4*)&Bs[row][scol] = ps;
        }
        __syncthreads();

        short8 af[4], bgf[4], bsf[4];
#pragma unroll
        for (int m = 0; m < 4; m++)
            af[m] = *(const short8*)&As[wr * 64 + m * 16 + lr][kb];
#pragma unroll
        for (int n = 0; n < 4; n++) {
            bgf[n] = *(const short8*)&Bg[wc * 64 + n * 16 + lr][kb];
            bsf[n] = *(const short8*)&Bs[wc * 64 + n * 16 + lr][kb];
        }
#pragma unroll
        for (int m = 0; m < 4; m++)
#pragma unroll
            for (int n = 0; n < 4; n++) {
                accg[m][n] = __builtin_amdgcn_mfma_f32_16x16x32_bf16(
                    af[m], bgf[n], accg[m][n], 0, 0, 0);
                accs[m][n] = __builtin_amdgcn_mfma_f32_16x16x32_bf16(
                    af[m], bsf[n], accs[m][n], 0, 0, 0);
            }
    }

    const int rowoff = (lane >> 4) * 4;
#pragma unroll
    for (int m = 0; m < 4; m++) {
        const int prow = rbase + wr * 64 + m * 16 + rowoff;
#pragma unroll
        for (int n = 0; n < 4; n++) {
            const int col = cbase + wc * 64 + n * 16 + lr;
            const float b1g = b1[(size_t)gate * 4096 + col];
            const float b1s = b1[(size_t)GATES * 4096 + col];
#pragma unroll
            for (int j = 0; j < 4; j++) {
                float vg = accg[m][n][j] + b1g;
                float vs = accs[m][n][j] + b1s;
                float sv = 0.9f * fmaxf(vg, 0.f) + fmaxf(vs, 0.f);
                s_out[(size_t)(prow + j) * 4096 + col] = f2b(sv);
            }
        }
    }
}

__global__ __launch_bounds__(256, 2)
void l2_fb(const unsigned short* __restrict__ s_in, const float* __restrict__ W2,
           const float* __restrict__ b2, unsigned short* __restrict__ h2)
{
    __shared__ __align__(16) unsigned short As[BM][LDSW_FB];
    __shared__ __align__(16) unsigned short Bt[BN][LDSW_FB];

    const int t = threadIdx.x;
    const int rbase = blockIdx.y * BM;
    const int cbase = blockIdx.x * BN;
    const int srow_t = t >> 3;
    const int scol   = (t & 7) * 4;

    f32x4 acc[4][4];
#pragma unroll
    for (int m = 0; m < 4; m++)
#pragma unroll
        for (int n = 0; n < 4; n++) acc[m][n] = (f32x4){0.f, 0.f, 0.f, 0.f};

    const int lane = t & 63;
    const int wid  = t >> 6;
    const int wr = wid >> 1, wc = wid & 1;
    const int lr = lane & 15;
    const int kb = (lane >> 4) * 8;

    for (int k0 = 0; k0 < 4096; k0 += BK) {
        __syncthreads();
#pragma unroll
        for (int rr = 0; rr < 4; rr++) {
            const int row = rr * 32 + srow_t;
            ushort4 av = *(const ushort4*)(s_in + (size_t)(rbase + row) * 4096 + k0 + scol);
            *(ushort4*)&As[row][scol] = av;
            float4 bv = *(const float4*)(W2 + (size_t)(cbase + row) * 4096 + k0 + scol);
            ushort4 pb;
            pb.x = f2b(bv.x); pb.y = f2b(bv.y); pb.z = f2b(bv.z); pb.w = f2b(bv.w);
            *(ushort4*)&Bt[row][scol] = pb;
        }
        __syncthreads();

        short8 af[4], bf[4];
#pragma unroll
        for (int m = 0; m < 4; m++)
            af[m] = *(const short8*)&As[wr * 64 + m * 16 + lr][kb];
#pragma unroll
        for (int n = 0; n < 4; n++)
            bf[n] = *(const short8*)&Bt[wc * 64 + n * 16 + lr][kb];
#pragma unroll
        for (int m = 0; m < 4; m++)
#pragma unroll
            for (int n = 0; n < 4; n++)
                acc[m][n] = __builtin_amdgcn_mfma_f32_16x16x32_bf16(
                    af[m], bf[n], acc[m][n], 0, 0, 0);
    }

    const int rowoff = (lane >> 4) * 4;
#pragma unroll
    for (int m = 0; m < 4; m++) {
        const int prow = rbase + wr * 64 + m * 16 + rowoff;
#pragma unroll
        for (int n = 0; n < 4; n++) {
            const int col = cbase + wc * 64 + n * 16 + lr;
            const float bb = b2[col];
#pragma unroll
            for (int j = 0; j < 4; j++) {
                float v = fmaxf(acc[m][n][j] + bb, 0.f);
                h2[(size_t)(prow + j) * 2048 + col] = f2b(v);
            }
        }
    }
}

__global__ __launch_bounds__(256, 2)
void l3_fb(const unsigned short* __restrict__ h2, const float* __restrict__ W3,
           const int* __restrict__ perm, float* __restrict__ out)
{
    __shared__ __align__(16) unsigned short As[BM][LDSW_FB];
    __shared__ __align__(16) unsigned short Bt[BN][LDSW_FB];

    const int t = threadIdx.x;
    const int rbase = blockIdx.y * BM;
    const int cbase = blockIdx.x * BN;
    const int srow_t = t >> 3;
    const int scol   = (t & 7) * 4;

    f32x4 acc[4][4];
#pragma unroll
    for (int m = 0; m < 4; m++)
#pragma unroll
        for (int n = 0; n < 4; n++) acc[m][n] = (f32x4){0.f, 0.f, 0.f, 0.f};

    const int lane = t & 63;
    const int wid  = t >> 6;
    const int wr = wid >> 1, wc = wid & 1;
    const int lr = lane & 15;
    const int kb = (lane >> 4) * 8;

    for (int k0 = 0; k0 < 2048; k0 += BK) {
        __syncthreads();
#pragma unroll
        for (int rr = 0; rr < 4; rr++) {
            const int row = rr * 32 + srow_t;
            ushort4 av = *(const ushort4*)(h2 + (size_t)(rbase + row) * 2048 + k0 + scol);
            *(ushort4*)&As[row][scol] = av;
            float4 bv = *(const float4*)(W3 + (size_t)(cbase + row) * 2048 + k0 + scol);
            ushort4 pb;
            pb.x = f2b(bv.x); pb.y = f2b(bv.y); pb.z = f2b(bv.z); pb.w = f2b(bv.w);
            *(ushort4*)&Bt[row][scol] = pb;
        }
        __syncthreads();

        short8 af[4], bf[4];
#pragma unroll
        for (int m = 0; m < 4; m++)
            af[m] = *(const short8*)&As[wr * 64 + m * 16 + lr][kb];
#pragma unroll
        for (int n = 0; n < 4; n++)
            bf[n] = *(const short8*)&Bt[wc * 64 + n * 16 + lr][kb];
#pragma unroll
        for (int m = 0; m < 4; m++)
#pragma unroll
            for (int n = 0; n < 4; n++)
                acc[m][n] = __builtin_amdgcn_mfma_f32_16x16x32_bf16(
                    af[m], bf[n], acc[m][n], 0, 0, 0);
    }

    const int rowoff = (lane >> 4) * 4;
#pragma unroll
    for (int m = 0; m < 4; m++) {
        const int prow = rbase + wr * 64 + m * 16 + rowoff;
#pragma unroll
        for (int n = 0; n < 4; n++) {
            const int col = cbase + wc * 64 + n * 16 + lr;
#pragma unroll
            for (int j = 0; j < 4; j++) {
                int orow = perm[prow + j];
                if (orow >= 0)
                    out[(size_t)orow * 1024 + col] = acc[m][n][j];
            }
        }
    }
}

// ---------------------------------------------------------------------------
extern "C" void kernel_launch(void* const* d_in, const int* in_sizes, int n_in,
                              void* d_out, int out_size, void* d_ws, size_t ws_size,
                              hipStream_t stream)
{
    const float* x   = (const float*)d_in[0];
    const int*   gid = (const int*)d_in[1];
    const float* W1  = (const float*)d_in[2];
    const float* b1  = (const float*)d_in[3];
    const float* W2  = (const float*)d_in[4];
    const float* b2  = (const float*)d_in[5];
    const float* W3  = (const float*)d_in[6];
    float* out = (float*)d_out;
    char* ws = (char*)d_ws;

    auto alignup = [](size_t v) { return (v + 255) & ~(size_t)255; };

    // ---- big (fast-path) layout ----
    size_t off = 0;
    const size_t perm_off = off; off = alignup(off + (size_t)NP * 4);
    const size_t tg_off   = off; off = alignup(off + (size_t)NROWT * 4);
    const size_t xbf_off  = off; off = alignup(off + (size_t)4097 * 1024 * 2);
    const size_t w1_off   = off; off = alignup(off + (size_t)36864 * 1024 * 2);
    const size_t w2_off   = off; off = alignup(off + (size_t)2048 * 4096 * 2);
    const size_t w3_off   = off; off = alignup(off + (size_t)1024 * 2048 * 2);
    const size_t sB_off   = off; off = alignup(off + (size_t)NP * 4096 * 2);
    const size_t h2B_off  = off; off = alignup(off + (size_t)NP * 2048 * 2);
    const size_t need_big = off;

    // ---- small (fallback) layout (round-2 verified) ----
    const size_t sS_off   = 32768;
    const size_t h2S_off  = sS_off + (size_t)NP * 4096 * 2;
    const size_t need_sm  = h2S_off + (size_t)NP * 2048 * 2;

    int* perm = (int*)(ws + perm_off);
    int* tile_gate = (int*)(ws + tg_off);

    if (ws_size >= need_big) {
        unsigned short* xbf  = (unsigned short*)(ws + xbf_off);
        unsigned short* w1bf = (unsigned short*)(ws + w1_off);
        unsigned short* w2bf = (unsigned short*)(ws + w2_off);
        unsigned short* w3bf = (unsigned short*)(ws + w3_off);
        unsigned short* s_perm = (unsigned short*)(ws + sB_off);
        unsigned short* h2 = (unsigned short*)(ws + h2B_off);
        unsigned short* zrow = xbf + (size_t)NROWS * 1024;   // row 4096

        bucket_kernel<<<1, 256, 0, stream>>>(gid, perm, tile_gate, zrow);
        cast_all_kernel<<<2048, 256, 0, stream>>>(
            x,  xbf,  (NROWS * 1024) / 8,
            W1, w1bf, (36864 * 1024) / 8,
            W2, w2bf, (2048 * 4096) / 8,
            W3, w3bf, (1024 * 2048) / 8);
        l1_fast<<<dim3(32, NROWT), 256, 0, stream>>>(xbf, w1bf, b1, perm, tile_gate, s_perm);
        l2_fast<<<dim3(16, NROWT), 256, 0, stream>>>(s_perm, w2bf, b2, perm, h2);
        l3_fast<<<dim3(16, NROWT), 256, 0, stream>>>(h2, w3bf, perm, out);
    } else if (ws_size >= need_sm) {
        // fallback: round-2 path, perm/tg at same offsets (0 / 20480)
        unsigned short* s_perm = (unsigned short*)(ws + sS_off);
        unsigned short* h2 = (unsigned short*)(ws + h2S_off);

        bucket_kernel<<<1, 256, 0, stream>>>(gid, perm, tile_gate, (unsigned short*)nullptr);
        l1_fb<<<dim3(32, NROWT), 256, 0, stream>>>(x, W1, b1, perm, tile_gate, s_perm);
        l2_fb<<<dim3(16, NROWT), 256, 0, stream>>>(s_perm, W2, b2, h2);
        l3_fb<<<dim3(8, NROWT), 256, 0, stream>>>(h2, W3, perm, out);
    }
    // else: ws too small even for fallback -> loud failure
}

// Round 12
// 530.517 us; speedup vs baseline: 1.0590x; 1.0348x over previous
//
#include <hip/hip_runtime.h>
#include <cstdint>

// ---------------------------------------------------------------------------
// GatedMLP: out = relu(relu(x@W1^T+b1) gated-blocksum @ W2^T + b2) @ W3^T
// N=4096, IN=1024, D=2048, G=8, 2D=4096, OUT=1024
// Round 12: resubmission of round-10/11 kernel (both benches = GPU
// acquisition timeouts, kernel never ran).  vs round-9 measured run:
//   - REVERT xcd_remap everywhere (r9 A/B: FETCH 86->193MB, l1 116->140us —
//     inputs are L3-resident; remap spread the instantaneous working set
//     across XCD-disjoint regions and thrashed L3)
//   + keep fully-pad row-tile early exit
//   + keep l3 retiled 128x64 (grid 640, 4 blocks/CU)
//   + keep merged cast kernel
// Keeps: bf16 pre-cast, gload_lds(16B), 2-way slot swizzle (conflicts=0),
// launch_bounds(256,2) on l1/l2, single-buffer 2-barrier loop (r6 base).
// ---------------------------------------------------------------------------

#define NP 5120       // padded row space: 4096 + 8*128 slack
#define NROWT 40      // NP / 128
#define NROWS 4096
#define GATES 8

typedef short short8 __attribute__((ext_vector_type(8)));
typedef unsigned short ushort8v __attribute__((ext_vector_type(8)));
typedef float f32x4 __attribute__((ext_vector_type(4)));

constexpr int BM = 128, BN = 128, BK = 32;
constexpr int BN3 = 64;               // l3 column-tile
constexpr int LDSW_FB = 40;           // fallback: 32 + 8 bf16 pad

__device__ __forceinline__ unsigned short f2b(float f) {
    __bf16 h = (__bf16)f;
    return __builtin_bit_cast(unsigned short, h);
}

// async global->LDS, 16 bytes per lane. LDS dest is wave-uniform base;
// HW writes lane i at base + i*16 (linear).
__device__ __forceinline__ void gload_lds16(const void* g, void* l) {
    __builtin_amdgcn_global_load_lds(
        (const __attribute__((address_space(1))) void*)g,
        (__attribute__((address_space(3))) void*)l, 16, 0, 0);
}

// LDS slot swizzle (verified r6: SQ_LDS_BANK_CONFLICT 7.86M -> 0): tile row r
// (64B = four 16B slots), logical slot q stored at q ^ ((r>>1)&3).
// Staging thread t (row = t>>2 [+64], slot = t&3):
//   swizzled source slot = (t&3) ^ ((t>>3)&3)
// Read lane (row = 16*q + lr, lr = lane&15):
//   slot = (lane>>4) ^ ((lr>>1)&3)

// ---------------------------------------------------------------------------
// Kernel 0: bucket rows by gate id into padded segments (+ zero-row init)
// ---------------------------------------------------------------------------
__global__ void bucket_kernel(const int* __restrict__ gid,
                              int* __restrict__ perm,
                              int* __restrict__ tile_gate,
                              unsigned short* __restrict__ zrow)  // 1024 bf16 or null
{
    __shared__ int cnt[GATES], pstart[GATES], cur[GATES];
    const int t = threadIdx.x;
    if (zrow) {
        ushort4 z; z.x = 0; z.y = 0; z.z = 0; z.w = 0;
        ((ushort4*)zrow)[t] = z;              // 256 threads x 4 = 1024 elems
    }
    if (t < GATES) cnt[t] = 0;
    __syncthreads();
    for (int i = t; i < NROWS; i += 256) atomicAdd(&cnt[gid[i]], 1);
    __syncthreads();
    if (t == 0) {
        int off = 0;
        for (int g = 0; g < GATES; g++) {
            pstart[g] = off;
            cur[g] = 0;
            off += (cnt[g] + 127) & ~127;
        }
    }
    __syncthreads();
    for (int i = t; i < NP; i += 256) perm[i] = -1;
    if (t < NROWT) {
        int r0 = t * 128;
        int tg = 0;
        for (int g = 0; g < GATES; g++) {
            int pc = (cnt[g] + 127) & ~127;
            if (r0 >= pstart[g] && r0 < pstart[g] + pc) tg = g;
        }
        tile_gate[t] = tg;
    }
    __syncthreads();
    for (int i = t; i < NROWS; i += 256) {
        int g = gid[i];
        int p = atomicAdd(&cur[g], 1);
        perm[pstart[g] + p] = i;
    }
}

// ---------------------------------------------------------------------------
// merged fp32 -> bf16 cast pass over 4 arrays (memory-bound, 8 f32/iter)
// ---------------------------------------------------------------------------
__global__ __launch_bounds__(256)
void cast_all_kernel(const float* __restrict__ s0, unsigned short* __restrict__ d0, int n0,
                     const float* __restrict__ s1, unsigned short* __restrict__ d1, int n1,
                     const float* __restrict__ s2, unsigned short* __restrict__ d2, int n2,
                     const float* __restrict__ s3, unsigned short* __restrict__ d3, int n3)
{
    const int e01 = n0 + n1, e012 = n0 + n1 + n2;
    const int total = e012 + n3;
    int i = blockIdx.x * 256 + threadIdx.x;
    const int stride = gridDim.x * 256;
    for (; i < total; i += stride) {
        const float* s; unsigned short* d; int j;
        if (i < n0)        { s = s0; d = d0; j = i; }
        else if (i < e01)  { s = s1; d = d1; j = i - n0; }
        else if (i < e012) { s = s2; d = d2; j = i - e01; }
        else               { s = s3; d = d3; j = i - e012; }
        const float4* s4 = (const float4*)(s + (size_t)j * 8);
        float4 a = s4[0], b = s4[1];
        ushort8v v;
        v[0] = f2b(a.x); v[1] = f2b(a.y); v[2] = f2b(a.z); v[3] = f2b(a.w);
        v[4] = f2b(b.x); v[5] = f2b(b.y); v[6] = f2b(b.z); v[7] = f2b(b.w);
        *(ushort8v*)(d + (size_t)j * 8) = v;
    }
}

// ---------------------------------------------------------------------------
// FAST PATH GEMMs (single-buffer r6 loop + early-exit; NO xcd remap)
// ---------------------------------------------------------------------------
__global__ __launch_bounds__(256, 2)
void l1_fast(const unsigned short* __restrict__ xbf,   // [4097][1024], row 4096 = zeros
             const unsigned short* __restrict__ W1bf,  // [36864][1024]
             const float* __restrict__ b1,
             const int* __restrict__ perm,
             const int* __restrict__ tile_gate,
             unsigned short* __restrict__ s_out)       // [NP][4096]
{
    __shared__ __align__(16) unsigned short As[BM][BK];
    __shared__ __align__(16) unsigned short Bg[BN][BK];
    __shared__ __align__(16) unsigned short Bs[BN][BK];

    const int rbase = blockIdx.y * BM;
    if (perm[rbase] < 0) return;            // fully-pad row tile
    const int cbase = blockIdx.x * BN;
    const int gate = tile_gate[blockIdx.y];

    const int t = threadIdx.x;
    const int srow  = t >> 2;                          // 0..63
    const int skcol = ((t & 3) ^ ((t >> 3) & 3)) * 8;  // swizzled source slot

    int g0 = perm[rbase + srow];      if (g0 < 0) g0 = NROWS;
    int g1 = perm[rbase + srow + 64]; if (g1 < 0) g1 = NROWS;

    const unsigned short* a0 = xbf + (size_t)g0 * 1024 + skcol;
    const unsigned short* a1 = xbf + (size_t)g1 * 1024 + skcol;
    const unsigned short* bg0 = W1bf + ((size_t)(gate * 4096 + cbase + srow)) * 1024 + skcol;
    const unsigned short* bg1 = bg0 + (size_t)64 * 1024;
    const unsigned short* bs0 = W1bf + ((size_t)(GATES * 4096 + cbase + srow)) * 1024 + skcol;
    const unsigned short* bs1 = bs0 + (size_t)64 * 1024;

    const int wchunk = (t >> 6) * 1024;   // byte offset of this wave's LDS chunk

    f32x4 accg[4][4], accs[4][4];
#pragma unroll
    for (int m = 0; m < 4; m++)
#pragma unroll
        for (int n = 0; n < 4; n++) {
            accg[m][n] = (f32x4){0.f, 0.f, 0.f, 0.f};
            accs[m][n] = (f32x4){0.f, 0.f, 0.f, 0.f};
        }

    const int lane = t & 63;
    const int wid  = t >> 6;
    const int wr = wid >> 1, wc = wid & 1;
    const int lr = lane & 15;
    const int kb = (((lane >> 4) ^ ((lr >> 1) & 3))) * 8;  // swizzled read slot

    for (int k0 = 0; k0 < 1024; k0 += BK) {
        gload_lds16(a0 + k0,  (char*)As + wchunk);
        gload_lds16(a1 + k0,  (char*)As + wchunk + 4096);
        gload_lds16(bg0 + k0, (char*)Bg + wchunk);
        gload_lds16(bg1 + k0, (char*)Bg + wchunk + 4096);
        gload_lds16(bs0 + k0, (char*)Bs + wchunk);
        gload_lds16(bs1 + k0, (char*)Bs + wchunk + 4096);
        __syncthreads();   // drains vmcnt before barrier

        short8 af[4];
#pragma unroll
        for (int m = 0; m < 4; m++)
            af[m] = *(const short8*)&As[wr * 64 + m * 16 + lr][kb];
        {
            short8 bf[4];
#pragma unroll
            for (int n = 0; n < 4; n++)
                bf[n] = *(const short8*)&Bg[wc * 64 + n * 16 + lr][kb];
#pragma unroll
            for (int m = 0; m < 4; m++)
#pragma unroll
                for (int n = 0; n < 4; n++)
                    accg[m][n] = __builtin_amdgcn_mfma_f32_16x16x32_bf16(
                        af[m], bf[n], accg[m][n], 0, 0, 0);
        }
        {
            short8 bf[4];
#pragma unroll
            for (int n = 0; n < 4; n++)
                bf[n] = *(const short8*)&Bs[wc * 64 + n * 16 + lr][kb];
#pragma unroll
            for (int m = 0; m < 4; m++)
#pragma unroll
                for (int n = 0; n < 4; n++)
                    accs[m][n] = __builtin_amdgcn_mfma_f32_16x16x32_bf16(
                        af[m], bf[n], accs[m][n], 0, 0, 0);
        }
        __syncthreads();
    }

    const int rowoff = (lane >> 4) * 4;
#pragma unroll
    for (int m = 0; m < 4; m++) {
        const int prow = rbase + wr * 64 + m * 16 + rowoff;
#pragma unroll
        for (int n = 0; n < 4; n++) {
            const int col = cbase + wc * 64 + n * 16 + lr;
            const float b1g = b1[(size_t)gate * 4096 + col];
            const float b1s = b1[(size_t)GATES * 4096 + col];
#pragma unroll
            for (int j = 0; j < 4; j++) {
                float vg = accg[m][n][j] + b1g;
                float vs = accs[m][n][j] + b1s;
                float sv = 0.9f * fmaxf(vg, 0.f) + fmaxf(vs, 0.f);
                s_out[(size_t)(prow + j) * 4096 + col] = f2b(sv);
            }
        }
    }
}

__global__ __launch_bounds__(256, 2)
void l2_fast(const unsigned short* __restrict__ s_in,   // [NP][4096]
             const unsigned short* __restrict__ W2bf,   // [2048][4096]
             const float* __restrict__ b2,
             const int* __restrict__ perm,
             unsigned short* __restrict__ h2)           // [NP][2048]
{
    __shared__ __align__(16) unsigned short As[BM][BK];
    __shared__ __align__(16) unsigned short Bt[BN][BK];

    const int rbase = blockIdx.y * BM;
    if (perm[rbase] < 0) return;            // fully-pad row tile
    const int cbase = blockIdx.x * BN;

    const int t = threadIdx.x;
    const int srow  = t >> 2;
    const int skcol = ((t & 3) ^ ((t >> 3) & 3)) * 8;

    const unsigned short* a0 = s_in + (size_t)(rbase + srow) * 4096 + skcol;
    const unsigned short* a1 = a0 + (size_t)64 * 4096;
    const unsigned short* b0 = W2bf + (size_t)(cbase + srow) * 4096 + skcol;
    const unsigned short* b1p = b0 + (size_t)64 * 4096;

    const int wchunk = (t >> 6) * 1024;

    f32x4 acc[4][4];
#pragma unroll
    for (int m = 0; m < 4; m++)
#pragma unroll
        for (int n = 0; n < 4; n++) acc[m][n] = (f32x4){0.f, 0.f, 0.f, 0.f};

    const int lane = t & 63;
    const int wid  = t >> 6;
    const int wr = wid >> 1, wc = wid & 1;
    const int lr = lane & 15;
    const int kb = (((lane >> 4) ^ ((lr >> 1) & 3))) * 8;

    for (int k0 = 0; k0 < 4096; k0 += BK) {
        gload_lds16(a0 + k0,  (char*)As + wchunk);
        gload_lds16(a1 + k0,  (char*)As + wchunk + 4096);
        gload_lds16(b0 + k0,  (char*)Bt + wchunk);
        gload_lds16(b1p + k0, (char*)Bt + wchunk + 4096);
        __syncthreads();

        short8 af[4], bf[4];
#pragma unroll
        for (int m = 0; m < 4; m++)
            af[m] = *(const short8*)&As[wr * 64 + m * 16 + lr][kb];
#pragma unroll
        for (int n = 0; n < 4; n++)
            bf[n] = *(const short8*)&Bt[wc * 64 + n * 16 + lr][kb];
#pragma unroll
        for (int m = 0; m < 4; m++)
#pragma unroll
            for (int n = 0; n < 4; n++)
                acc[m][n] = __builtin_amdgcn_mfma_f32_16x16x32_bf16(
                    af[m], bf[n], acc[m][n], 0, 0, 0);
        __syncthreads();
    }

    const int rowoff = (lane >> 4) * 4;
#pragma unroll
    for (int m = 0; m < 4; m++) {
        const int prow = rbase + wr * 64 + m * 16 + rowoff;
#pragma unroll
        for (int n = 0; n < 4; n++) {
            const int col = cbase + wc * 64 + n * 16 + lr;
            const float bb = b2[col];
#pragma unroll
            for (int j = 0; j < 4; j++) {
                float v = fmaxf(acc[m][n][j] + bb, 0.f);
                h2[(size_t)(prow + j) * 2048 + col] = f2b(v);
            }
        }
    }
}

// l3: 128x64 tiles, grid (1024/64=16, 40) = 640 blocks. Per wave (2x2): 64x32,
// acc[4][2] = 32 AGPR; ~<=100 unified regs -> (256,4) safe (no spill).
__global__ __launch_bounds__(256, 4)
void l3_fast(const unsigned short* __restrict__ h2,     // [NP][2048]
             const unsigned short* __restrict__ W3bf,   // [1024][2048]
             const int* __restrict__ perm,
             float* __restrict__ out)                   // [4096][1024]
{
    __shared__ __align__(16) unsigned short As[BM][BK];   // 8 KB
    __shared__ __align__(16) unsigned short Bt[BN3][BK];  // 4 KB

    const int rbase = blockIdx.y * BM;
    if (perm[rbase] < 0) return;            // fully-pad row tile
    const int cbase = blockIdx.x * BN3;

    const int t = threadIdx.x;
    const int srow  = t >> 2;
    const int skcol = ((t & 3) ^ ((t >> 3) & 3)) * 8;

    const unsigned short* a0 = h2 + (size_t)(rbase + srow) * 2048 + skcol;
    const unsigned short* a1 = a0 + (size_t)64 * 2048;
    const unsigned short* b0 = W3bf + (size_t)(cbase + srow) * 2048 + skcol; // srow<64 rows

    const int wchunk = (t >> 6) * 1024;

    f32x4 acc[4][2];
#pragma unroll
    for (int m = 0; m < 4; m++)
#pragma unroll
        for (int n = 0; n < 2; n++) acc[m][n] = (f32x4){0.f, 0.f, 0.f, 0.f};

    const int lane = t & 63;
    const int wid  = t >> 6;
    const int wr = wid >> 1, wc = wid & 1;
    const int lr = lane & 15;
    const int kb = (((lane >> 4) ^ ((lr >> 1) & 3))) * 8;

    for (int k0 = 0; k0 < 2048; k0 += BK) {
        gload_lds16(a0 + k0, (char*)As + wchunk);
        gload_lds16(a1 + k0, (char*)As + wchunk + 4096);
        gload_lds16(b0 + k0, (char*)Bt + wchunk);      // waves 0..3 x 1KB = 4KB tile
        __syncthreads();

        short8 af[4], bf[2];
#pragma unroll
        for (int m = 0; m < 4; m++)
            af[m] = *(const short8*)&As[wr * 64 + m * 16 + lr][kb];
#pragma unroll
        for (int n = 0; n < 2; n++)
            bf[n] = *(const short8*)&Bt[wc * 32 + n * 16 + lr][kb];
#pragma unroll
        for (int m = 0; m < 4; m++)
#pragma unroll
            for (int n = 0; n < 2; n++)
                acc[m][n] = __builtin_amdgcn_mfma_f32_16x16x32_bf16(
                    af[m], bf[n], acc[m][n], 0, 0, 0);
        __syncthreads();
    }

    const int rowoff = (lane >> 4) * 4;
#pragma unroll
    for (int m = 0; m < 4; m++) {
        const int prow = rbase + wr * 64 + m * 16 + rowoff;
#pragma unroll
        for (int n = 0; n < 2; n++) {
            const int col = cbase + wc * 32 + n * 16 + lr;
#pragma unroll
            for (int j = 0; j < 4; j++) {
                int orow = perm[prow + j];
                if (orow >= 0)
                    out[(size_t)orow * 1024 + col] = acc[m][n][j];
            }
        }
    }
}

// ---------------------------------------------------------------------------
// FALLBACK PATH (round-2 verified kernels, fp32 reg-staged)
// ---------------------------------------------------------------------------
__global__ __launch_bounds__(256, 2)
void l1_fb(const float* __restrict__ x, const float* __restrict__ W1,
           const float* __restrict__ b1, const int* __restrict__ perm,
           const int* __restrict__ tile_gate, unsigned short* __restrict__ s_out)
{
    __shared__ __align__(16) unsigned short As[BM][LDSW_FB];
    __shared__ __align__(16) unsigned short Bg[BN][LDSW_FB];
    __shared__ __align__(16) unsigned short Bs[BN][LDSW_FB];

    const int t = threadIdx.x;
    const int rbase = blockIdx.y * BM;
    const int cbase = blockIdx.x * BN;
    const int gate = tile_gate[blockIdx.y];
    const int srow_t = t >> 3;
    const int scol   = (t & 7) * 4;

    int grow[4];
#pragma unroll
    for (int rr = 0; rr < 4; rr++) grow[rr] = perm[rbase + rr * 32 + srow_t];

    const float* Bgp = W1 + ((size_t)gate * 4096 + cbase) * 1024;
    const float* Bsp = W1 + ((size_t)GATES * 4096 + cbase) * 1024;

    f32x4 accg[4][4], accs[4][4];
#pragma unroll
    for (int m = 0; m < 4; m++)
#pragma unroll
        for (int n = 0; n < 4; n++) {
            accg[m][n] = (f32x4){0.f, 0.f, 0.f, 0.f};
            accs[m][n] = (f32x4){0.f, 0.f, 0.f, 0.f};
        }

    const int lane = t & 63;
    const int wid  = t >> 6;
    const int wr = wid >> 1, wc = wid & 1;
    const int lr = lane & 15;
    const int kb = (lane >> 4) * 8;

    for (int k0 = 0; k0 < 1024; k0 += BK) {
        __syncthreads();
#pragma unroll
        for (int rr = 0; rr < 4; rr++) {
            const int row = rr * 32 + srow_t;
            float4 av = make_float4(0.f, 0.f, 0.f, 0.f);
            if (grow[rr] >= 0)
                av = *(const float4*)(x + (size_t)grow[rr] * 1024 + k0 + scol);
            ushort4 pa;
            pa.x = f2b(av.x); pa.y = f2b(av.y); pa.z = f2b(av.z); pa.w = f2b(av.w);
            *(ushort4*)&As[row][scol] = pa;

            float4 gv = *(const float4*)(Bgp + (size_t)row * 1024 + k0 + scol);
            ushort4 pg;
            pg.x = f2b(gv.x); pg.y = f2b(gv.y); pg.z = f2b(gv.z); pg.w = f2b(gv.w);
            *(ushort4*)&Bg[row][scol] = pg;

            float4 sv = *(const float4*)(Bsp + (size_t)row * 1024 + k0 + scol);
            ushort4 ps;
            ps.x = f2b(sv.x); ps.y = f2b(sv.y); ps.z = f2b(sv.z); ps.w = f2b(sv.w);
            *(ushort4*)&Bs[row][scol] = ps;
        }
        __syncthreads();

        short8 af[4], bgf[4], bsf[4];
#pragma unroll
        for (int m = 0; m < 4; m++)
            af[m] = *(const short8*)&As[wr * 64 + m * 16 + lr][kb];
#pragma unroll
        for (int n = 0; n < 4; n++) {
            bgf[n] = *(const short8*)&Bg[wc * 64 + n * 16 + lr][kb];
            bsf[n] = *(const short8*)&Bs[wc * 64 + n * 16 + lr][kb];
        }
#pragma unroll
        for (int m = 0; m < 4; m++)
#pragma unroll
            for (int n = 0; n < 4; n++) {
                accg[m][n] = __builtin_amdgcn_mfma_f32_16x16x32_bf16(
                    af[m], bgf[n], accg[m][n], 0, 0, 0);
                accs[m][n] = __builtin_amdgcn_mfma_f32_16x16x32_bf16(
                    af[m], bsf[n], accs[m][n], 0, 0, 0);
            }
    }

    const int rowoff = (lane >> 4) * 4;
#pragma unroll
    for (int m = 0; m < 4; m++) {
        const int prow = rbase + wr * 64 + m * 16 + rowoff;
#pragma unroll
        for (int n = 0; n < 4; n++) {
            const int col = cbase + wc * 64 + n * 16 + lr;
            const float b1g = b1[(size_t)gate * 4096 + col];
            const float b1s = b1[(size_t)GATES * 4096 + col];
#pragma unroll
            for (int j = 0; j < 4; j++) {
                float vg = accg[m][n][j] + b1g;
                float vs = accs[m][n][j] + b1s;
                float sv = 0.9f * fmaxf(vg, 0.f) + fmaxf(vs, 0.f);
                s_out[(size_t)(prow + j) * 4096 + col] = f2b(sv);
            }
        }
    }
}

__global__ __launch_bounds__(256, 2)
void l2_fb(const unsigned short* __restrict__ s_in, const float* __restrict__ W2,
           const float* __restrict__ b2, unsigned short* __restrict__ h2)
{
    __shared__ __align__(16) unsigned short As[BM][LDSW_FB];
    __shared__ __align__(16) unsigned short Bt[BN][LDSW_FB];

    const int t = threadIdx.x;
    const int rbase = blockIdx.y * BM;
    const int cbase = blockIdx.x * BN;
    const int srow_t = t >> 3;
    const int scol   = (t & 7) * 4;

    f32x4 acc[4][4];
#pragma unroll
    for (int m = 0; m < 4; m++)
#pragma unroll
        for (int n = 0; n < 4; n++) acc[m][n] = (f32x4){0.f, 0.f, 0.f, 0.f};

    const int lane = t & 63;
    const int wid  = t >> 6;
    const int wr = wid >> 1, wc = wid & 1;
    const int lr = lane & 15;
    const int kb = (lane >> 4) * 8;

    for (int k0 = 0; k0 < 4096; k0 += BK) {
        __syncthreads();
#pragma unroll
        for (int rr = 0; rr < 4; rr++) {
            const int row = rr * 32 + srow_t;
            ushort4 av = *(const ushort4*)(s_in + (size_t)(rbase + row) * 4096 + k0 + scol);
            *(ushort4*)&As[row][scol] = av;
            float4 bv = *(const float4*)(W2 + (size_t)(cbase + row) * 4096 + k0 + scol);
            ushort4 pb;
            pb.x = f2b(bv.x); pb.y = f2b(bv.y); pb.z = f2b(bv.z); pb.w = f2b(bv.w);
            *(ushort4*)&Bt[row][scol] = pb;
        }
        __syncthreads();

        short8 af[4], bf[4];
#pragma unroll
        for (int m = 0; m < 4; m++)
            af[m] = *(const short8*)&As[wr * 64 + m * 16 + lr][kb];
#pragma unroll
        for (int n = 0; n < 4; n++)
            bf[n] = *(const short8*)&Bt[wc * 64 + n * 16 + lr][kb];
#pragma unroll
        for (int m = 0; m < 4; m++)
#pragma unroll
            for (int n = 0; n < 4; n++)
                acc[m][n] = __builtin_amdgcn_mfma_f32_16x16x32_bf16(
                    af[m], bf[n], acc[m][n], 0, 0, 0);
    }

    const int rowoff = (lane >> 4) * 4;
#pragma unroll
    for (int m = 0; m < 4; m++) {
        const int prow = rbase + wr * 64 + m * 16 + rowoff;
#pragma unroll
        for (int n = 0; n < 4; n++) {
            const int col = cbase + wc * 64 + n * 16 + lr;
            const float bb = b2[col];
#pragma unroll
            for (int j = 0; j < 4; j++) {
                float v = fmaxf(acc[m][n][j] + bb, 0.f);
                h2[(size_t)(prow + j) * 2048 + col] = f2b(v);
            }
        }
    }
}

__global__ __launch_bounds__(256, 2)
void l3_fb(const unsigned short* __restrict__ h2, const float* __restrict__ W3,
           const int* __restrict__ perm, float* __restrict__ out)
{
    __shared__ __align__(16) unsigned short As[BM][LDSW_FB];
    __shared__ __align__(16) unsigned short Bt[BN][LDSW_FB];

    const int t = threadIdx.x;
    const int rbase = blockIdx.y * BM;
    const int cbase = blockIdx.x * BN;
    const int srow_t = t >> 3;
    const int scol   = (t & 7) * 4;

    f32x4 acc[4][4];
#pragma unroll
    for (int m = 0; m < 4; m++)
#pragma unroll
        for (int n = 0; n < 4; n++) acc[m][n] = (f32x4){0.f, 0.f, 0.f, 0.f};

    const int lane = t & 63;
    const int wid  = t >> 6;
    const int wr = wid >> 1, wc = wid & 1;
    const int lr = lane & 15;
    const int kb = (lane >> 4) * 8;

    for (int k0 = 0; k0 < 2048; k0 += BK) {
        __syncthreads();
#pragma unroll
        for (int rr = 0; rr < 4; rr++) {
            const int row = rr * 32 + srow_t;
            ushort4 av = *(const ushort4*)(h2 + (size_t)(rbase + row) * 2048 + k0 + scol);
            *(ushort4*)&As[row][scol] = av;
            float4 bv = *(const float4*)(W3 + (size_t)(cbase + row) * 2048 + k0 + scol);
            ushort4 pb;
            pb.x = f2b(bv.x); pb.y = f2b(bv.y); pb.z = f2b(bv.z); pb.w = f2b(bv.w);
            *(ushort4*)&Bt[row][scol] = pb;
        }
        __syncthreads();

        short8 af[4], bf[4];
#pragma unroll
        for (int m = 0; m < 4; m++)
            af[m] = *(const short8*)&As[wr * 64 + m * 16 + lr][kb];
#pragma unroll
        for (int n = 0; n < 4; n++)
            bf[n] = *(const short8*)&Bt[wc * 64 + n * 16 + lr][kb];
#pragma unroll
        for (int m = 0; m < 4; m++)
#pragma unroll
            for (int n = 0; n < 4; n++)
                acc[m][n] = __builtin_amdgcn_mfma_f32_16x16x32_bf16(
                    af[m], bf[n], acc[m][n], 0, 0, 0);
    }

    const int rowoff = (lane >> 4) * 4;
#pragma unroll
    for (int m = 0; m < 4; m++) {
        const int prow = rbase + wr * 64 + m * 16 + rowoff;
#pragma unroll
        for (int n = 0; n < 4; n++) {
            const int col = cbase + wc * 64 + n * 16 + lr;
#pragma unroll
            for (int j = 0; j < 4; j++) {
                int orow = perm[prow + j];
                if (orow >= 0)
                    out[(size_t)orow * 1024 + col] = acc[m][n][j];
            }
        }
    }
}

// ---------------------------------------------------------------------------
extern "C" void kernel_launch(void* const* d_in, const int* in_sizes, int n_in,
                              void* d_out, int out_size, void* d_ws, size_t ws_size,
                              hipStream_t stream)
{
    const float* x   = (const float*)d_in[0];
    const int*   gid = (const int*)d_in[1];
    const float* W1  = (const float*)d_in[2];
    const float* b1  = (const float*)d_in[3];
    const float* W2  = (const float*)d_in[4];
    const float* b2  = (const float*)d_in[5];
    const float* W3  = (const float*)d_in[6];
    float* out = (float*)d_out;
    char* ws = (char*)d_ws;

    auto alignup = [](size_t v) { return (v + 255) & ~(size_t)255; };

    // ---- big (fast-path) layout ----
    size_t off = 0;
    const size_t perm_off = off; off = alignup(off + (size_t)NP * 4);
    const size_t tg_off   = off; off = alignup(off + (size_t)NROWT * 4);
    const size_t xbf_off  = off; off = alignup(off + (size_t)4097 * 1024 * 2);
    const size_t w1_off   = off; off = alignup(off + (size_t)36864 * 1024 * 2);
    const size_t w2_off   = off; off = alignup(off + (size_t)2048 * 4096 * 2);
    const size_t w3_off   = off; off = alignup(off + (size_t)1024 * 2048 * 2);
    const size_t sB_off   = off; off = alignup(off + (size_t)NP * 4096 * 2);
    const size_t h2B_off  = off; off = alignup(off + (size_t)NP * 2048 * 2);
    const size_t need_big = off;

    // ---- small (fallback) layout (round-2 verified) ----
    const size_t sS_off   = 32768;
    const size_t h2S_off  = sS_off + (size_t)NP * 4096 * 2;
    const size_t need_sm  = h2S_off + (size_t)NP * 2048 * 2;

    int* perm = (int*)(ws + perm_off);
    int* tile_gate = (int*)(ws + tg_off);

    if (ws_size >= need_big) {
        unsigned short* xbf  = (unsigned short*)(ws + xbf_off);
        unsigned short* w1bf = (unsigned short*)(ws + w1_off);
        unsigned short* w2bf = (unsigned short*)(ws + w2_off);
        unsigned short* w3bf = (unsigned short*)(ws + w3_off);
        unsigned short* s_perm = (unsigned short*)(ws + sB_off);
        unsigned short* h2 = (unsigned short*)(ws + h2B_off);
        unsigned short* zrow = xbf + (size_t)NROWS * 1024;   // row 4096

        bucket_kernel<<<1, 256, 0, stream>>>(gid, perm, tile_gate, zrow);
        cast_all_kernel<<<2048, 256, 0, stream>>>(
            x,  xbf,  (NROWS * 1024) / 8,
            W1, w1bf, (36864 * 1024) / 8,
            W2, w2bf, (2048 * 4096) / 8,
            W3, w3bf, (1024 * 2048) / 8);
        l1_fast<<<dim3(32, NROWT), 256, 0, stream>>>(xbf, w1bf, b1, perm, tile_gate, s_perm);
        l2_fast<<<dim3(16, NROWT), 256, 0, stream>>>(s_perm, w2bf, b2, perm, h2);
        l3_fast<<<dim3(16, NROWT), 256, 0, stream>>>(h2, w3bf, perm, out);
    } else if (ws_size >= need_sm) {
        // fallback: round-2 path, perm/tg at same offsets (0 / 20480)
        unsigned short* s_perm = (unsigned short*)(ws + sS_off);
        unsigned short* h2 = (unsigned short*)(ws + h2S_off);

        bucket_kernel<<<1, 256, 0, stream>>>(gid, perm, tile_gate, (unsigned short*)nullptr);
        l1_fb<<<dim3(32, NROWT), 256, 0, stream>>>(x, W1, b1, perm, tile_gate, s_perm);
        l2_fb<<<dim3(16, NROWT), 256, 0, stream>>>(s_perm, W2, b2, h2);
        l3_fb<<<dim3(8, NROWT), 256, 0, stream>>>(h2, W3, perm, out);
    }
    // else: ws too small even for fallback -> loud failure
}